// Round 1
// baseline (156.672 us; speedup 1.0000x reference)
//
#include <hip/hip_runtime.h>
#include <hip/hip_bf16.h>
#include <stdint.h>

#define DEV __device__ __forceinline__

typedef __attribute__((ext_vector_type(8))) short short8;   // 8 bf16 (4 VGPRs)
typedef __attribute__((ext_vector_type(4))) float f32x4;    // MFMA acc

#define TWO_LOG2E 2.8853900817779268f   // 2*log2(e): exp(2x) == exp2(x*TWO_LOG2E)

// ---------------------------------------------------------------- helpers
DEV unsigned short f2bf(float f) {           // fp32 -> bf16, RNE
  uint32_t u = __float_as_uint(f);
  u += 0x7FFFu + ((u >> 16) & 1u);
  return (unsigned short)(u >> 16);
}

DEV uint2 pk4(float4 f) {                    // 4 fp32 -> 4 bf16 (packed cvt)
  union { __hip_bfloat162 h; unsigned u; } a, b;
  a.h = __float22bfloat162_rn(make_float2(f.x, f.y));
  b.h = __float22bfloat162_rn(make_float2(f.z, f.w));
  return make_uint2(a.u, b.u);
}

DEV short8 mk8(uint2 lo, uint2 hi) {
  union { short8 s; uint4 u; } t;
  t.u = make_uint4(lo.x, lo.y, hi.x, hi.y);
  return t.s;
}

DEV uint32_t rotl32(uint32_t x, int r) { return (x << r) | (x >> (32 - r)); }

// JAX Threefry-2x32 with key = (0, 42)  (jax.random.key(42))
DEV void threefry_0_42(uint32_t x0, uint32_t x1, uint32_t& o0, uint32_t& o1) {
  const uint32_t ks0 = 0u, ks1 = 42u, ks2 = 0x1BD11BDAu ^ 42u;
  x0 += ks0; x1 += ks1;
#define TFR(r) { x0 += x1; x1 = rotl32(x1, (r)); x1 ^= x0; }
  TFR(13) TFR(15) TFR(26) TFR(6)  x0 += ks1; x1 += ks2 + 1u;
  TFR(17) TFR(29) TFR(16) TFR(24) x0 += ks2; x1 += ks0 + 2u;
  TFR(13) TFR(15) TFR(26) TFR(6)  x0 += ks0; x1 += ks1 + 3u;
  TFR(17) TFR(29) TFR(16) TFR(24) x0 += ks1; x1 += ks2 + 4u;
  TFR(13) TFR(15) TFR(26) TFR(6)  x0 += ks2; x1 += ks0 + 5u;
#undef TFR
  o0 = x0; o1 = x1;
}

DEV float wredmax(float v) {
#pragma unroll
  for (int off = 32; off > 0; off >>= 1) v = fmaxf(v, __shfl_xor(v, off));
  return v;
}
DEV float wredsum(float v) {
#pragma unroll
  for (int off = 32; off > 0; off >>= 1) v += __shfl_xor(v, off);
  return v;
}

// ---------------------------------------------------------------- fused transposes (1 dispatch)
__global__ __launch_bounds__(256) void transpose_all(const float* __restrict__ Wctx,
                                                     const float* __restrict__ Wq,
                                                     const float* __restrict__ Wout,
                                                     unsigned short* __restrict__ WctxT,
                                                     unsigned short* __restrict__ WqT,
                                                     unsigned short* __restrict__ WoutT) {
  __shared__ float tile[64][65];
  const int b = blockIdx.x;
  const float* src; unsigned short* dst; int R, C, br, bc;
  if (b < 8)       { src = Wctx; dst = WctxT; R = 512;  C = 64;  br = b * 64;        bc = 0; }
  else if (b < 16) { src = Wq;   dst = WqT;   R = 512;  C = 64;  br = (b - 8) * 64;  bc = 0; }
  else { int i = b - 16; src = Wout; dst = WoutT; R = 1024; C = 512; br = (i & 15) * 64; bc = (i >> 4) * 64; }
  const int tid = threadIdx.x;
  const int lr = tid >> 4, lc4 = (tid & 15) * 4;
#pragma unroll
  for (int i = 0; i < 4; ++i) {
    float4 v = *(const float4*)(src + (long)(br + lr + i * 16) * C + bc + lc4);
    tile[lr + i * 16][lc4 + 0] = v.x;
    tile[lr + i * 16][lc4 + 1] = v.y;
    tile[lr + i * 16][lc4 + 2] = v.z;
    tile[lr + i * 16][lc4 + 3] = v.w;
  }
  __syncthreads();
#pragma unroll
  for (int i = 0; i < 4; ++i) {
    int crow = lr + i * 16;
    ushort4 o;
    o.x = f2bf(tile[lc4 + 0][crow]);
    o.y = f2bf(tile[lc4 + 1][crow]);
    o.z = f2bf(tile[lc4 + 2][crow]);
    o.w = f2bf(tile[lc4 + 3][crow]);
    *(ushort4*)(dst + (long)(bc + crow) * R + br + lc4) = o;
  }
}

// ---------------------------------------------------------------- merged uh+wq MFMA GEMM
// blocks 0..255: uhT[n][d][s] = TWO_LOG2E*(mb @ WctxT^T)  (TRANSPOSED output for scores)
// blocks 256..271: wq[m][d]   = TWO_LOG2E*(input @ WqT^T) (row-major)
__global__ __launch_bounds__(256) void gemm_uhwq(const float* __restrict__ mb,
                                                 const float* __restrict__ input,
                                                 const unsigned short* __restrict__ WctxT,
                                                 const unsigned short* __restrict__ WqT,
                                                 float* __restrict__ uhT,
                                                 float* __restrict__ wqo) {
  __shared__ unsigned short As[64][32];
  __shared__ unsigned short Bs[64][32];
  const int tid = threadIdx.x;
  const int bx = blockIdx.x;
  const float* A;  const unsigned short* BT;  int mbase;
  if (bx < 256) { A = mb;    BT = WctxT; mbase = bx * 64; }
  else          { A = input; BT = WqT;   mbase = (bx - 256) * 64; }
  const int srow = tid >> 2, kc = tid & 3;
  const int scol = ((kc ^ (srow & 3)) * 8);
  const int wave = tid >> 6, lane = tid & 63;
  const int wm = (wave >> 1) * 32, wn = (wave & 1) * 32;
  const int q = lane >> 4, r = lane & 15;
  const int c0 = ((q ^ (r & 3)) * 8);
  const float* ap = A + (long)(mbase + srow) * 512 + kc * 8;
  const unsigned short* bp = BT + (long)srow * 512 + kc * 8;
  f32x4 acc[2][2];
#pragma unroll
  for (int i = 0; i < 2; ++i)
#pragma unroll
    for (int j = 0; j < 2; ++j) acc[i][j] = (f32x4){0.f, 0.f, 0.f, 0.f};

  float4 fa0 = *(const float4*)(ap);
  float4 fa1 = *(const float4*)(ap + 4);
  uint4 fb = *(const uint4*)(bp);
  for (int k0 = 0; k0 < 512; k0 += 32) {
    uint2 p0 = pk4(fa0), p1 = pk4(fa1);
    *(uint4*)&As[srow][scol] = make_uint4(p0.x, p0.y, p1.x, p1.y);
    *(uint4*)&Bs[srow][scol] = fb;
    __syncthreads();
    if (k0 + 32 < 512) {
      fa0 = *(const float4*)(ap + k0 + 32);
      fa1 = *(const float4*)(ap + k0 + 36);
      fb = *(const uint4*)(bp + k0 + 32);
    }
    short8 a0 = *(const short8*)&As[wm + r][c0];
    short8 a1 = *(const short8*)&As[wm + 16 + r][c0];
    short8 b0 = *(const short8*)&Bs[wn + r][c0];
    short8 b1 = *(const short8*)&Bs[wn + 16 + r][c0];
    acc[0][0] = __builtin_amdgcn_mfma_f32_16x16x32_bf16(a0, b0, acc[0][0], 0, 0, 0);
    acc[0][1] = __builtin_amdgcn_mfma_f32_16x16x32_bf16(a0, b1, acc[0][1], 0, 0, 0);
    acc[1][0] = __builtin_amdgcn_mfma_f32_16x16x32_bf16(a1, b0, acc[1][0], 0, 0, 0);
    acc[1][1] = __builtin_amdgcn_mfma_f32_16x16x32_bf16(a1, b1, acc[1][1], 0, 0, 0);
    __syncthreads();
  }
#pragma unroll
  for (int i2 = 0; i2 < 2; ++i2)
#pragma unroll
    for (int j2 = 0; j2 < 2; ++j2) {
      int gcol = wn + j2 * 16 + r;                      // d
      int m = mbase + wm + i2 * 16 + q * 4;             // 4 consecutive rows via reg
      if (bx < 256) {                                   // transposed: uhT[n][d][s]
        int n = m >> 10, s0 = m & 1023;
        float4 o;
        o.x = acc[i2][j2][0] * TWO_LOG2E;
        o.y = acc[i2][j2][1] * TWO_LOG2E;
        o.z = acc[i2][j2][2] * TWO_LOG2E;
        o.w = acc[i2][j2][3] * TWO_LOG2E;
        *(float4*)(uhT + (long)n * 65536 + (long)gcol * 1024 + s0) = o;
      } else {
#pragma unroll
        for (int reg = 0; reg < 4; ++reg)
          wqo[(long)(m + reg) * 64 + gcol] = acc[i2][j2][reg] * TWO_LOG2E;
      }
    }
}

// ---------------------------------------------------------------- P = input @ W_top + b  (one-time, shared by both views)
// grid (16,16), 64x32 tile. A = input fp32 (pk4-staged), B = WoutT rows, k in [0,512).
__global__ __launch_bounds__(256) void gemm_pre(const float* __restrict__ input,
                                                const unsigned short* __restrict__ WoutT,
                                                const float* __restrict__ bout,
                                                float* __restrict__ P) {
  __shared__ unsigned short As[64][32];
  __shared__ unsigned short Bs[32][32];
  const int tid = threadIdx.x;
  const int mbase = blockIdx.x * 64, nbase = blockIdx.y * 32;
  const int srow = tid >> 2, kc = tid & 3;
  const int scol = ((kc ^ (srow & 3)) * 8);
  const int wave = tid >> 6, lane = tid & 63;
  const int wm = (wave >> 1) * 32, wn = (wave & 1) * 16;
  const int q = lane >> 4, r = lane & 15;
  const int c0 = ((q ^ (r & 3)) * 8);
  const float* ap = input + (long)(mbase + srow) * 512 + kc * 8;
  const int brow = (tid & 127) >> 2;
  const unsigned short* bp = WoutT + (long)(nbase + brow) * 1024 + kc * 8;
  f32x4 acc[2];
  acc[0] = (f32x4){0.f, 0.f, 0.f, 0.f};
  acc[1] = (f32x4){0.f, 0.f, 0.f, 0.f};

  float4 fa0 = *(const float4*)(ap);
  float4 fa1 = *(const float4*)(ap + 4);
  uint4 fb;
  if (tid < 128) fb = *(const uint4*)(bp);
  for (int k0 = 0; k0 < 512; k0 += 32) {
    uint2 p0 = pk4(fa0), p1 = pk4(fa1);
    *(uint4*)&As[srow][scol] = make_uint4(p0.x, p0.y, p1.x, p1.y);
    if (tid < 128) *(uint4*)&Bs[brow][(kc ^ (brow & 3)) * 8] = fb;
    __syncthreads();
    int kn = k0 + 32;
    if (kn < 512) {
      fa0 = *(const float4*)(ap + kn);
      fa1 = *(const float4*)(ap + kn + 4);
      if (tid < 128) fb = *(const uint4*)(bp + kn);
    }
    short8 a0 = *(const short8*)&As[wm + r][c0];
    short8 a1 = *(const short8*)&As[wm + 16 + r][c0];
    short8 b0 = *(const short8*)&Bs[wn + r][c0];
    acc[0] = __builtin_amdgcn_mfma_f32_16x16x32_bf16(a0, b0, acc[0], 0, 0, 0);
    acc[1] = __builtin_amdgcn_mfma_f32_16x16x32_bf16(a1, b0, acc[1], 0, 0, 0);
    __syncthreads();
  }
#pragma unroll
  for (int i2 = 0; i2 < 2; ++i2) {
    int gcol = nbase + wn + r;
    float bb = bout[gcol];
#pragma unroll
    for (int reg = 0; reg < 4; ++reg) {
      int grow = mbase + wm + i2 * 16 + q * 4 + reg;
      P[(long)grow * 512 + gcol] = acc[i2][reg] + bb;
    }
  }
}

// ---------------------------------------------------------------- merged-vt MFMA ctx GEMM (bf16 A, shared B)
// grid (16,16) = n x dblock, 512 threads / 8 waves. Waves 0-3: alpha-ctx, 4-7: yal-ctx.
// B (mb columns) register-loaded once per wave-pair, shared across both views.
__global__ __launch_bounds__(512) void gemm_ctx_mfma(const unsigned short* __restrict__ alpha,
                                                     const unsigned short* __restrict__ yal,
                                                     const float* __restrict__ mb,
                                                     unsigned short* __restrict__ ctx) {
  __shared__ unsigned short As[2][64][32];
  const int tid = threadIdx.x;
  const int n = blockIdx.x, dbase = blockIdx.y * 32;
  // staging: threads 0..255 stage alpha tile, 256..511 stage yal tile
  const int half = tid >> 8, st = tid & 255;
  const int srow = st >> 2, kc = st & 3;
  const int scol = ((kc ^ (srow & 3)) * 8);
  const unsigned short* Ab = (half ? yal : alpha) + (long)n * 65536 + (long)srow * 1024 + kc * 8;
  // compute roles
  const int wave = tid >> 6, lane = tid & 63;
  const int vt = wave >> 2, wm = ((wave >> 1) & 1) * 32, wn = (wave & 1) * 16;
  const int q = lane >> 4, r = lane & 15;
  const int c0 = ((q ^ (r & 3)) * 8);
  const float* bcol = mb + (long)n * 524288 + dbase + wn + r;  // + s*512
  f32x4 acc[2];
  acc[0] = (f32x4){0.f, 0.f, 0.f, 0.f};
  acc[1] = (f32x4){0.f, 0.f, 0.f, 0.f};

  uint4 fa = *(const uint4*)(Ab);
  float bv[8];
#pragma unroll
  for (int j = 0; j < 8; ++j) bv[j] = bcol[(long)(q * 8 + j) * 512];

  for (int k0 = 0; k0 < 1024; k0 += 32) {
    *(uint4*)&As[half][srow][scol] = fa;
    __syncthreads();
    float4 blo = make_float4(bv[0], bv[1], bv[2], bv[3]);
    float4 bhi = make_float4(bv[4], bv[5], bv[6], bv[7]);
    short8 b0 = mk8(pk4(blo), pk4(bhi));
    if (k0 + 32 < 1024) {
      fa = *(const uint4*)(Ab + k0 + 32);
#pragma unroll
      for (int j = 0; j < 8; ++j) bv[j] = bcol[(long)(k0 + 32 + q * 8 + j) * 512];
    }
    short8 a0 = *(const short8*)&As[vt][wm + r][c0];
    short8 a1 = *(const short8*)&As[vt][wm + 16 + r][c0];
    acc[0] = __builtin_amdgcn_mfma_f32_16x16x32_bf16(a0, b0, acc[0], 0, 0, 0);
    acc[1] = __builtin_amdgcn_mfma_f32_16x16x32_bf16(a1, b0, acc[1], 0, 0, 0);
    __syncthreads();
  }
#pragma unroll
  for (int i2 = 0; i2 < 2; ++i2) {
    int gcol = dbase + wn + r;
#pragma unroll
    for (int reg = 0; reg < 4; ++reg) {
      long grow = (long)vt * 1024 + n * 64 + wm + i2 * 16 + q * 4 + reg;
      ctx[grow * 512 + gcol] = f2bf(acc[i2][reg]);
    }
  }
}

// ---------------------------------------------------------------- output GEMM: out = tanh(P + ctx @ W_bot)
// grid (32,16). A = ctx bf16 (direct staging), B = WoutT k in [512,1024), acc init from P.
__global__ __launch_bounds__(256) void gemm_out_mfma(const unsigned short* __restrict__ ctx,
                                                     const unsigned short* __restrict__ WoutT,
                                                     const float* __restrict__ P,
                                                     float* __restrict__ out) {
  __shared__ unsigned short As[64][32];
  __shared__ unsigned short Bs[32][32];
  const int tid = threadIdx.x;
  const int mbase = blockIdx.x * 64, nbase = blockIdx.y * 32;
  const int srow = tid >> 2, kc = tid & 3;
  const int scol = ((kc ^ (srow & 3)) * 8);
  const int wave = tid >> 6, lane = tid & 63;
  const int wm = (wave >> 1) * 32, wn = (wave & 1) * 16;
  const int q = lane >> 4, r = lane & 15;
  const int c0 = ((q ^ (r & 3)) * 8);
  const unsigned short* ap = ctx + (long)(mbase + srow) * 512 + kc * 8;
  const int brow = (tid & 127) >> 2;
  const unsigned short* bp = WoutT + (long)(nbase + brow) * 1024 + 512 + kc * 8;
  // acc init from P (per-view shared pre-product + bias)
  f32x4 acc[2];
#pragma unroll
  for (int i2 = 0; i2 < 2; ++i2) {
    int pcol = nbase + wn + r;
#pragma unroll
    for (int reg = 0; reg < 4; ++reg) {
      int prow = (mbase + wm + i2 * 16 + q * 4 + reg) & 1023;
      acc[i2][reg] = P[(long)prow * 512 + pcol];
    }
  }

  uint4 fa = *(const uint4*)(ap);
  uint4 fb;
  if (tid < 128) fb = *(const uint4*)(bp);
  for (int k0 = 0; k0 < 512; k0 += 32) {
    *(uint4*)&As[srow][scol] = fa;
    if (tid < 128) *(uint4*)&Bs[brow][(kc ^ (brow & 3)) * 8] = fb;
    __syncthreads();
    int kn = k0 + 32;
    if (kn < 512) {
      fa = *(const uint4*)(ap + kn);
      if (tid < 128) fb = *(const uint4*)(bp + kn);
    }
    short8 a0 = *(const short8*)&As[wm + r][c0];
    short8 a1 = *(const short8*)&As[wm + 16 + r][c0];
    short8 b0 = *(const short8*)&Bs[wn + r][c0];
    acc[0] = __builtin_amdgcn_mfma_f32_16x16x32_bf16(a0, b0, acc[0], 0, 0, 0);
    acc[1] = __builtin_amdgcn_mfma_f32_16x16x32_bf16(a1, b0, acc[1], 0, 0, 0);
    __syncthreads();
  }
#pragma unroll
  for (int i2 = 0; i2 < 2; ++i2) {
    int gcol = nbase + wn + r;
#pragma unroll
    for (int reg = 0; reg < 4; ++reg) {
      int grow = mbase + wm + i2 * 16 + q * 4 + reg;
      float z = acc[i2][reg];
      float rc = __builtin_amdgcn_rcpf(1.f + __builtin_amdgcn_exp2f(z * TWO_LOG2E));
      out[(long)grow * 512 + gcol] = fmaf(-2.f, rc, 1.f);
    }
  }
}

// ---------------------------------------------------------------- scores + softmax + gumbel (bf16 outputs)
// uhT[n][d][s] layout: thread owns 4 CONSECUTIVE s (s0 = 4*tid) -> every global
// load is wave-contiguous (1 KB/instr). wq2/v via LDS broadcast (conflict-free).
// uhT/wq2 prescaled by 2*log2(e): v.tanh = sumv - 2*sum v[d]*rcp(1+exp2(u+w)).
__global__ __launch_bounds__(256) void scores_kernel(const float* __restrict__ uhT,
                                                     const float* __restrict__ wq2,
                                                     const float* __restrict__ v,
                                                     unsigned short* __restrict__ alpha_g,
                                                     unsigned short* __restrict__ y_g) {
  const int tid = threadIdx.x;
  const int nt = blockIdx.x;           // n*64 + t
  const int n = nt >> 6;
  __shared__ float wvs[64];
  __shared__ float vvs[64];
  __shared__ float red[4];
  if (tid < 64) {
    wvs[tid] = wq2[nt * 64 + tid];
    vvs[tid] = v[tid];
  }
  __syncthreads();

  float sumv = 0.f;
#pragma unroll
  for (int d = 0; d < 64; d += 4) {
    float4 vv = *(const float4*)&vvs[d];
    sumv += vv.x + vv.y + vv.z + vv.w;
  }

  const float* un = uhT + (long)n * 65536 + tid * 4;   // + d*1024
  float4 racc = make_float4(0.f, 0.f, 0.f, 0.f);
  for (int db = 0; db < 64; db += 8) {
    float4 ub[8];
#pragma unroll
    for (int j = 0; j < 8; ++j) ub[j] = *(const float4*)(un + (long)(db + j) * 1024);
#pragma unroll
    for (int j = 0; j < 8; ++j) {
      float w = wvs[db + j], vvj = vvs[db + j];
      racc.x = fmaf(vvj, __builtin_amdgcn_rcpf(1.f + __builtin_amdgcn_exp2f(ub[j].x + w)), racc.x);
      racc.y = fmaf(vvj, __builtin_amdgcn_rcpf(1.f + __builtin_amdgcn_exp2f(ub[j].y + w)), racc.y);
      racc.z = fmaf(vvj, __builtin_amdgcn_rcpf(1.f + __builtin_amdgcn_exp2f(ub[j].z + w)), racc.z);
      racc.w = fmaf(vvj, __builtin_amdgcn_rcpf(1.f + __builtin_amdgcn_exp2f(ub[j].w + w)), racc.w);
    }
  }
  float lsc[4];
  lsc[0] = fmaf(-2.f, racc.x, sumv);
  lsc[1] = fmaf(-2.f, racc.y, sumv);
  lsc[2] = fmaf(-2.f, racc.z, sumv);
  lsc[3] = fmaf(-2.f, racc.w, sumv);

  // ---- log_softmax over S=1024 ----
  const int wv = tid >> 6, ln = tid & 63;
  float m = fmaxf(fmaxf(lsc[0], lsc[1]), fmaxf(lsc[2], lsc[3]));
  m = wredmax(m);
  if (ln == 0) red[wv] = m;
  __syncthreads();
  m = fmaxf(fmaxf(red[0], red[1]), fmaxf(red[2], red[3]));
  __syncthreads();
  float ss = 0.f;
#pragma unroll
  for (int i = 0; i < 4; ++i) ss += __expf(lsc[i] - m);
  ss = wredsum(ss);
  if (ln == 0) red[wv] = ss;
  __syncthreads();
  ss = red[0] + red[1] + red[2] + red[3];
  const float logl = __logf(ss);
  __syncthreads();

  // ---- alpha + gumbel (JAX partitionable threefry, key=(0,42); bits = o0^o1) ----
  const uint32_t jbase = (uint32_t)nt * 1024u + (uint32_t)tid * 4u;
  float ys[4];
  float4 av;
#pragma unroll
  for (int i = 0; i < 4; ++i) {
    float la = lsc[i] - m - logl;
    ((float*)&av)[i] = __expf(la);
    uint32_t o0, o1;
    threefry_0_42(0u, jbase + i, o0, o1);
    uint32_t bits = o0 ^ o1;
    float u = __uint_as_float((bits >> 9) | 0x3f800000u) - 1.0f;
    float g = -__logf(-__logf(u + 1e-20f) + 1e-20f);
    ys[i] = (la + g) * 2.0f;                           // /TEMPERATURE (0.5)
  }
  {
    uint2 pa = pk4(av);                                 // bf16 rounding == old pk4 in gemm_ctx
    *(uint2*)(alpha_g + (long)nt * 1024 + tid * 4) = pa;
  }

  // ---- softmax over ys ----
  float m2 = fmaxf(fmaxf(ys[0], ys[1]), fmaxf(ys[2], ys[3]));
  m2 = wredmax(m2);
  if (ln == 0) red[wv] = m2;
  __syncthreads();
  m2 = fmaxf(fmaxf(red[0], red[1]), fmaxf(red[2], red[3]));
  __syncthreads();
  float s2 = 0.f;
  float4 ye;
#pragma unroll
  for (int i = 0; i < 4; ++i) { ((float*)&ye)[i] = __expf(ys[i] - m2); s2 += ((float*)&ye)[i]; }
  s2 = wredsum(s2);
  if (ln == 0) red[wv] = s2;
  __syncthreads();
  s2 = red[0] + red[1] + red[2] + red[3];
  const float rinv = __fdividef(1.f, s2);
  ye.x *= rinv; ye.y *= rinv; ye.z *= rinv; ye.w *= rinv;
  {
    uint2 py = pk4(ye);
    *(uint2*)(y_g + (long)nt * 1024 + tid * 4) = py;
  }
}

// ---------------------------------------------------------------- launch
// ws layout (float units):
//   uhT      [0       , 1048576)   fp32 [16][64][1024] TRANSPOSED, prescaled
//   wq       [1048576 , 1114112)   fp32 [1024][64], prescaled
//   alpha_bf [1114112 , 1638400)   bf16 [16][64][1024]
//   yal_bf   [1638400 , 2162688)   bf16 [16][64][1024]
//   WctxT    [2162688 , 2179072)   bf16 [64][512]
//   WqT      [2179072 , 2195456)   bf16 [64][512]
//   WoutT    [2195456 , 2457600)   bf16 [512][1024]
//   ctx_bf   [2457600 , 2981888)   bf16 [2048][512]
//   P        [2981888 , 3506176)   fp32 [1024][512]  (input @ W_top + b, shared by both views)
extern "C" void kernel_launch(void* const* d_in, const int* in_sizes, int n_in,
                              void* d_out, int out_size, void* d_ws, size_t ws_size,
                              hipStream_t stream) {
  const float* input = (const float*)d_in[0];   // [16,64,512]
  const float* mb    = (const float*)d_in[1];   // [16,1024,512]
  const float* W_q   = (const float*)d_in[2];   // [512,64]
  const float* W_ctx = (const float*)d_in[3];   // [512,64]
  const float* v     = (const float*)d_in[4];   // [64]
  const float* W_out = (const float*)d_in[5];   // [1024,512]
  const float* b_out = (const float*)d_in[6];   // [512]
  float* out = (float*)d_out;                   // [2,16,64,512]
  float* ws = (float*)d_ws;

  float* uhT   = ws;
  float* wq    = ws + 1048576;
  unsigned short* alpha_bf = (unsigned short*)(ws + 1114112);
  unsigned short* yal_bf   = (unsigned short*)(ws + 1638400);
  unsigned short* WctxT = (unsigned short*)(ws + 2162688);
  unsigned short* WqT   = (unsigned short*)(ws + 2179072);
  unsigned short* WoutT = (unsigned short*)(ws + 2195456);
  unsigned short* ctxb  = (unsigned short*)(ws + 2457600);
  float* P = ws + 2981888;

  transpose_all<<<144, 256, 0, stream>>>(W_ctx, W_q, W_out, WctxT, WqT, WoutT);
  gemm_uhwq<<<272, 256, 0, stream>>>(mb, input, WctxT, WqT, uhT, wq);
  gemm_pre<<<dim3(16, 16), 256, 0, stream>>>(input, WoutT, b_out, P);
  scores_kernel<<<1024, 256, 0, stream>>>(uhT, wq, v, alpha_bf, yal_bf);
  gemm_ctx_mfma<<<dim3(16, 16), 512, 0, stream>>>(alpha_bf, yal_bf, mb, ctxb);
  gemm_out_mfma<<<dim3(32, 16), 256, 0, stream>>>(ctxb, WoutT, P, out);
}